// Round 1
// 306.780 us; speedup vs baseline: 1.0054x; 1.0054x over previous
//
#include <hip/hip_runtime.h>

// GenerateNodes: out[n,t,o,k] = sum_c mix[n,t,c] * W[k,o,c] + b[k,o]
// mix = concat(x [16384,3200], seeds [16384,15])  -> GEMM M=16384, K=3215, Ncol=60
// Strategy: bf16 MFMA 16x16x32, A direct-from-global (fp32->bf16 in regs),
// B prepacked to fragment order in a static __device__ array (NO d_ws use --
// the 800 MiB workspace re-poison fill dominated the previous measurement).
// K split 4-ways across the block's 4 waves (16 rows/block, 1024 blocks,
// 4096 waves = 16 waves/CU) to fix the 1-wave/SIMD latency limit; fp32
// partials combined through padded LDS.

#define NROWS    16384
#define CIN      3200
#define SEED_K   15
#define LIN_IN   3215
#define NCOL     60
#define KB_MAIN  100          // 3200 / 32
#define KB_TOT   101          // + tail block covering the 15 seed channels
#define KB_CHUNK 25           // KB_MAIN / 4 waves
#define WB_ELEMS (KB_TOT * 4 * 64 * 8)   // 206848 ushorts

typedef __attribute__((ext_vector_type(8))) __bf16 bf16x8;
typedef __attribute__((ext_vector_type(4))) float f32x4;
typedef __attribute__((ext_vector_type(8))) unsigned short ushort8;

// Static device-global B fragments: avoids d_ws entirely.
__device__ unsigned short Wb_g[WB_ELEMS];

__device__ inline unsigned short f2bf_rne(float f) {
    unsigned int u = __builtin_bit_cast(unsigned int, f);
    u += 0x7fffu + ((u >> 16) & 1u);
    return (unsigned short)(u >> 16);
}

__device__ inline bf16x8 to_bf16x8(f32x4 a0, f32x4 a1) {
    ushort8 u;
    u[0] = f2bf_rne(a0[0]); u[1] = f2bf_rne(a0[1]);
    u[2] = f2bf_rne(a0[2]); u[3] = f2bf_rne(a0[3]);
    u[4] = f2bf_rne(a1[0]); u[5] = f2bf_rne(a1[1]);
    u[6] = f2bf_rne(a1[2]); u[7] = f2bf_rne(a1[3]);
    return __builtin_bit_cast(bf16x8, u);
}

// Pack W[20,3,3215] fp32 into bf16 B-fragment order:
// Wb[kb][nt][lane][jj] = B[k = kb*32 + (lane>>4)*8 + jj][n = nt*16 + (lane&15)]
// where B[c][j] = W[j%20][j/20][c]; zero-pad k>=3215 and n>=60.
__global__ void prep_B(const float* __restrict__ W) {
    int idx = blockIdx.x * blockDim.x + threadIdx.x;
    if (idx >= WB_ELEMS) return;
    int jj   = idx & 7;
    int lane = (idx >> 3) & 63;
    int nt   = (idx >> 9) & 3;
    int kb   = idx >> 11;
    int k = kb * 32 + (lane >> 4) * 8 + jj;
    int n = nt * 16 + (lane & 15);
    float v = 0.0f;
    if (k < LIN_IN && n < NCOL) {
        int o = n / 20, kn = n % 20;
        v = W[(kn * 3 + o) * LIN_IN + k];
    }
    Wb_g[idx] = f2bf_rne(v);
}

__global__ __launch_bounds__(256, 4) void gen_nodes_gemm(
    const float* __restrict__ x, const float* __restrict__ seeds,
    const float* __restrict__ b, float* __restrict__ out) {
    const int lane = threadIdx.x & 63;
    const int wave = threadIdx.x >> 6;      // wave = K-chunk id, 0..3
    const int quad = lane >> 4;
    const int l15  = lane & 15;
    const int row_base = blockIdx.x * 16;   // 16 rows per block (all 4 waves)
    const int arow = row_base + l15;        // A-operand row for this lane

    const float* xrow = x + (size_t)arow * CIN + quad * 8;

    f32x4 acc[4];
#pragma unroll
    for (int i = 0; i < 4; ++i) acc[i] = (f32x4){0.f, 0.f, 0.f, 0.f};

    const int kb0 = wave * KB_CHUNK;
    const int kb1 = kb0 + KB_CHUNK;

#pragma unroll 2
    for (int kb = kb0; kb < kb1; ++kb) {
        const f32x4* ap = (const f32x4*)(xrow + kb * 32);
        f32x4 a0 = ap[0];
        f32x4 a1 = ap[1];
        const unsigned short* bb = Wb_g + (size_t)kb * 2048 + lane * 8;
        bf16x8 b0 = *(const bf16x8*)(bb);
        bf16x8 b1 = *(const bf16x8*)(bb + 512);
        bf16x8 b2 = *(const bf16x8*)(bb + 1024);
        bf16x8 b3 = *(const bf16x8*)(bb + 1536);
        bf16x8 af = to_bf16x8(a0, a1);
        acc[0] = __builtin_amdgcn_mfma_f32_16x16x32_bf16(af, b0, acc[0], 0, 0, 0);
        acc[1] = __builtin_amdgcn_mfma_f32_16x16x32_bf16(af, b1, acc[1], 0, 0, 0);
        acc[2] = __builtin_amdgcn_mfma_f32_16x16x32_bf16(af, b2, acc[2], 0, 0, 0);
        acc[3] = __builtin_amdgcn_mfma_f32_16x16x32_bf16(af, b3, acc[3], 0, 0, 0);
    }

    // Tail MFMA block on wave 3: the 15 seed channels (k = 3200..3214).
    if (wave == 3) {
        const float* srow = seeds + (size_t)arow * SEED_K;
        f32x4 s0 = {0.f, 0.f, 0.f, 0.f}, s1 = {0.f, 0.f, 0.f, 0.f};
#pragma unroll
        for (int j = 0; j < 4; ++j) {
            int c = quad * 8 + j;
            if (c < SEED_K) s0[j] = srow[c];
            if (c + 4 < SEED_K) s1[j] = srow[c + 4];
        }
        bf16x8 af = to_bf16x8(s0, s1);
        const unsigned short* bb = Wb_g + (size_t)KB_MAIN * 2048 + lane * 8;
        bf16x8 b0 = *(const bf16x8*)(bb);
        bf16x8 b1 = *(const bf16x8*)(bb + 512);
        bf16x8 b2 = *(const bf16x8*)(bb + 1024);
        bf16x8 b3 = *(const bf16x8*)(bb + 1536);
        acc[0] = __builtin_amdgcn_mfma_f32_16x16x32_bf16(af, b0, acc[0], 0, 0, 0);
        acc[1] = __builtin_amdgcn_mfma_f32_16x16x32_bf16(af, b1, acc[1], 0, 0, 0);
        acc[2] = __builtin_amdgcn_mfma_f32_16x16x32_bf16(af, b2, acc[2], 0, 0, 0);
        acc[3] = __builtin_amdgcn_mfma_f32_16x16x32_bf16(af, b3, acc[3], 0, 0, 0);
    }

    // Combine the 4 K-chunk partials through LDS (stride 68 floats: the
    // 4-quad access lands on two disjoint 16-bank halves -> free 2-way).
    __shared__ float red[3][16][68];
    if (wave != 0) {
#pragma unroll
        for (int nt = 0; nt < 4; ++nt)
#pragma unroll
            for (int r = 0; r < 4; ++r)
                red[wave - 1][quad * 4 + r][nt * 16 + l15] = acc[nt][r];
    }
    __syncthreads();

    // Epilogue on wave 0: C/D layout col = lane&15, row = quad*4 + reg.
    if (wave == 0) {
#pragma unroll
        for (int nt = 0; nt < 4; ++nt) {
            int j = nt * 16 + l15;
            if (j < NCOL) {
                float bias = b[(j % 20) * 3 + (j / 20)];
#pragma unroll
                for (int r = 0; r < 4; ++r) {
                    int m = quad * 4 + r;
                    float v = acc[nt][r] + red[0][m][j] + red[1][m][j]
                            + red[2][m][j] + bias;
                    out[(size_t)(row_base + m) * NCOL + j] = v;
                }
            }
        }
    }
}

extern "C" void kernel_launch(void* const* d_in, const int* in_sizes, int n_in,
                              void* d_out, int out_size, void* d_ws, size_t ws_size,
                              hipStream_t stream) {
    const float* x     = (const float*)d_in[0];
    const float* seeds = (const float*)d_in[1];
    const float* W     = (const float*)d_in[2];
    const float* b     = (const float*)d_in[3];
    float* out = (float*)d_out;
    (void)d_ws; (void)ws_size;

    prep_B<<<(WB_ELEMS + 255) / 256, 256, 0, stream>>>(W);
    gen_nodes_gemm<<<NROWS / 16, 256, 0, stream>>>(x, seeds, b, out);
}